// Round 6
// baseline (402.364 us; speedup 1.0000x reference)
//
#include <hip/hip_runtime.h>
#include <stdint.h>

typedef unsigned short u16;
typedef unsigned int u32;
typedef float f32x4 __attribute__((ext_vector_type(4)));
typedef int   i32x4 __attribute__((ext_vector_type(4)));
typedef __bf16 bf16x8 __attribute__((ext_vector_type(8)));
typedef u16 u16x4 __attribute__((ext_vector_type(4)));

constexpr int S_LEN = 4096;
constexpr int HID   = 2048;
constexpr int WIN   = 2048;

__device__ __forceinline__ u32 f2bf_u(float f) {
  u32 u = __builtin_bit_cast(u32, f);
  return (u + 0x7fffu + ((u >> 16) & 1u)) >> 16;
}
__device__ __forceinline__ float bf2f(u16 u) {
  return __builtin_bit_cast(float, ((u32)u) << 16);
}
__device__ __forceinline__ void mfma16(f32x4& acc, i32x4 a, i32x4 b) {
  acc = __builtin_amdgcn_mfma_f32_16x16x32_bf16(
      __builtin_bit_cast(bf16x8, a), __builtin_bit_cast(bf16x8, b), acc, 0, 0, 0);
}
__device__ __forceinline__ void gload_lds16(const u16* g, u16* l) {
  __builtin_amdgcn_global_load_lds((const __attribute__((address_space(1))) u32*)g,
                                   (__attribute__((address_space(3))) u32*)l, 16, 0, 0);
}

// ---------------- fp32 -> bf16 convert (8 elems/thread) ----------------
__global__ __launch_bounds__(256) void cvt_bf16_kernel(const float* __restrict__ src,
                                                       u16* __restrict__ dst, int n8) {
  int t = blockIdx.x * 256 + threadIdx.x;
  if (t >= n8) return;
  const f32x4* s = (const f32x4*)src + (size_t)t * 2;
  f32x4 a = s[0], b = s[1];
  i32x4 o;
  o.x = (int)(f2bf_u(a.x) | (f2bf_u(a.y) << 16));
  o.y = (int)(f2bf_u(a.z) | (f2bf_u(a.w) << 16));
  o.z = (int)(f2bf_u(b.x) | (f2bf_u(b.y) << 16));
  o.w = (int)(f2bf_u(b.z) | (f2bf_u(b.w) << 16));
  *((i32x4*)dst + t) = o;
}

// ---------------- RoPE cos/sin table: [S][64] each ----------------
__global__ __launch_bounds__(256) void rope_table_kernel(float* __restrict__ cs,
                                                         float* __restrict__ sn) {
  int t = blockIdx.x * 256 + threadIdx.x;  // S*64 threads
  int d = t & 63, s = t >> 6;
  float inv = exp2f(-(float)d * 0.20762050593046014f);  // log2(10000)/64
  float f = (float)s * inv;
  cs[t] = cosf(f);
  sn[t] = sinf(f);
}

// ---------------- in-place RoPE on [S][NH*128] bf16, 4 d per thread -------
template <int NH>
__global__ __launch_bounds__(256) void rope_apply_kernel(u16* __restrict__ X,
                                                         const float* __restrict__ cs,
                                                         const float* __restrict__ sn) {
  int t = blockIdx.x * 256 + threadIdx.x;  // S*NH*16 threads
  int d0 = (t & 15) * 4;
  int r = t >> 4;
  int h = r % NH;
  int s = r / NH;
  f32x4 c = *(const f32x4*)&cs[(s << 6) | d0];
  f32x4 si = *(const f32x4*)&sn[(s << 6) | d0];
  u16* p = X + (size_t)s * (NH * 128) + h * 128 + d0;
  u16x4 a = *(u16x4*)p, b = *(u16x4*)(p + 64);
  u16x4 oa, ob;
#pragma unroll
  for (int j = 0; j < 4; ++j) {
    float x1 = bf2f(a[j]), x2 = bf2f(b[j]);
    oa[j] = (u16)f2bf_u(x1 * c[j] - x2 * si[j]);
    ob[j] = (u16)f2bf_u(x2 * c[j] + x1 * si[j]);
  }
  *(u16x4*)p = oa;
  *(u16x4*)(p + 64) = ob;
}

// ---------------- GEMM: C[M][N] = A[M][K] * B[N][K]^T, bf16 in, fp32 acc ----
// OUT_MODE 0: bf16 C[row*N+col]
// OUT_MODE 1: V tiled layout for attention (see attn_kernel PV fragment)
// OUT_MODE 2: fp32 C[row*N+col]
template <int OUT_MODE>
__global__ __launch_bounds__(256) void gemm_bt_kernel(const u16* __restrict__ A,
                                                      const u16* __restrict__ B,
                                                      void* __restrict__ Cv,
                                                      int K, int N) {
  __shared__ __attribute__((aligned(16))) u16 sA[128 * 64];
  __shared__ __attribute__((aligned(16))) u16 sB[128 * 64];
  const int lane = threadIdx.x & 63;
  const int w = threadIdx.x >> 6;
  const int g = lane >> 4, ln = lane & 15;

  // bijective XCD swizzle (nwg % 8 == 0 for all our grids)
  int wgid = blockIdx.y * gridDim.x + blockIdx.x;
  const int nwg = gridDim.x * gridDim.y;
  wgid = (wgid & 7) * (nwg >> 3) + (wgid >> 3);
  const int brow = (wgid / gridDim.x) * 128;
  const int bcol = (wgid % gridDim.x) * 128;
  const int wr = (w >> 1) * 64, wc = (w & 1) * 64;

  f32x4 acc[4][4] = {};

  const int sr = w * 32 + (lane >> 3);
  const int scol = (lane & 7) * 8;
  const u16* Abase = A + (size_t)(brow + sr) * K + scol;
  const u16* Bbase = B + (size_t)(bcol + sr) * K + scol;
  u16* sAdst = &sA[w * 2048];
  u16* sBdst = &sB[w * 2048];

  for (int k0 = 0; k0 < K; k0 += 64) {
    __syncthreads();
#pragma unroll
    for (int i = 0; i < 4; ++i) {
      gload_lds16(Abase + (size_t)i * 8 * K + k0, sAdst + i * 512);
      gload_lds16(Bbase + (size_t)i * 8 * K + k0, sBdst + i * 512);
    }
    __syncthreads();
#pragma unroll
    for (int kk = 0; kk < 2; ++kk) {
      i32x4 af[4], bfr[4];
#pragma unroll
      for (int m = 0; m < 4; ++m)
        af[m] = *(const i32x4*)&sA[(wr + m * 16 + ln) * 64 + kk * 32 + g * 8];
#pragma unroll
      for (int n = 0; n < 4; ++n)
        bfr[n] = *(const i32x4*)&sB[(wc + n * 16 + ln) * 64 + kk * 32 + g * 8];
#pragma unroll
      for (int m = 0; m < 4; ++m)
#pragma unroll
        for (int n = 0; n < 4; ++n) mfma16(acc[m][n], af[m], bfr[n]);
    }
  }

  const int orow0 = brow + wr + g * 4;
  const int ocol0 = bcol + wc + ln;
#pragma unroll
  for (int m = 0; m < 4; ++m)
#pragma unroll
    for (int n = 0; n < 4; ++n)
#pragma unroll
      for (int j = 0; j < 4; ++j) {
        int row = orow0 + m * 16 + j;
        int col = ocol0 + n * 16;
        float v = acc[m][n][j];
        if constexpr (OUT_MODE == 0) {
          ((u16*)Cv)[(size_t)row * N + col] = (u16)f2bf_u(v);
        } else if constexpr (OUT_MODE == 1) {
          // V tiled: row = s, col = kvh*128 + d
          int d = col & 127, kvh = col >> 7;
          int T = row >> 5, ks = row & 31;
          int t = ks >> 4, gg = (ks >> 2) & 3, e = (t << 2) | (ks & 3);
          size_t idx = (size_t)kvh * S_LEN * 128 + (size_t)T * 4096 +
                       (size_t)d * 32 + ((size_t)(gg ^ ((d >> 1) & 3)) << 3) + e;
          ((u16*)Cv)[idx] = (u16)f2bf_u(v);
        } else {
          ((float*)Cv)[(size_t)row * N + col] = v;
        }
      }
}

// ---------------- flash attention, sliding window, GQA, 2-way KV-split -----
// grid: 1024 blocks = (2 chunks x 32 q-tiles x 16 heads), XCD-swizzled.
// 4 waves x 32 q-rows. Swapped QK^T: lane owns q-row.
// 3-buffer LDS ring, prefetch depth 2, counted vmcnt + raw barriers (T3/T4).
__global__ __launch_bounds__(256) void attn_kernel(const u16* __restrict__ Q,
                                                   const u16* __restrict__ Kb,
                                                   const u16* __restrict__ Vt,
                                                   u16* __restrict__ opart,
                                                   float* __restrict__ mpart,
                                                   float* __restrict__ lpart) {
  __shared__ __attribute__((aligned(16))) u16 sK[3][32 * 128];
  __shared__ __attribute__((aligned(16))) u16 sV[3][32 * 128];

  const int lane = threadIdx.x & 63;
  const int w = threadIdx.x >> 6;
  const int g = lane >> 4, ln = lane & 15;

  const int o = blockIdx.x;                       // 1024
  const int wgid = ((o & 7) << 7) | (o >> 3);     // XCD swizzle (bijective)
  const int chunk = wgid & 1;
  const int qt = 31 - ((wgid >> 1) & 31);         // heavy tiles first
  const int h = wgid >> 6;
  const int kvh = h >> 2;
  const int qb = qt * 128;
  const int qr0 = qb + w * 32;

  // Q fragments (B-operand): qf in {0,1}: rows qr0+qf*16+ln, d-chunks c*32+g*8
  i32x4 aq[2][4];
#pragma unroll
  for (int qf = 0; qf < 2; ++qf) {
    const u16* qp = Q + (size_t)(qr0 + qf * 16 + ln) * HID + h * 128 + g * 8;
#pragma unroll
    for (int c = 0; c < 4; ++c) aq[qf][c] = *(const i32x4*)(qp + c * 32);
  }
  // drain Q loads so loop vmcnt counts only staged tiles
  asm volatile("s_waitcnt vmcnt(0)" ::: "memory");

  f32x4 oacc[2][8] = {};
  float mrun[2] = {-1e30f, -1e30f};
  float lrun[2] = {0.f, 0.f};

  int lo = qb - (WIN - 1);
  if (lo < 0) lo = 0;
  lo &= ~31;
  const int nt_full = ((qb + 128) - lo) >> 5;
  const int nt0 = nt_full >> 1;
  const int lo_c = lo + (chunk ? nt0 * 32 : 0);
  const int nt = chunk ? nt_full - nt0 : nt0;  // >= 2 always

  const u16* Vbase = Vt + (size_t)kvh * S_LEN * 128;
  const float scale = 0.088388347648318447f;  // 1/sqrt(128)

#define STAGE(KB, BUF)                                                         \
  {                                                                            \
    const int _kb = (KB);                                                      \
    _Pragma("unroll") for (int i = 0; i < 2; ++i) {                            \
      const int i4g = i * 4 + g;                                               \
      gload_lds16(Kb + (size_t)(_kb + w * 8 + i4g) * 512 + kvh * 128 +         \
                      ((ln ^ i4g) << 3),                                       \
                  &sK[BUF][w * 1024 + i * 512]);                               \
      gload_lds16(Vbase + (size_t)(_kb >> 5) * 4096 + w * 1024 + i * 512 +     \
                      lane * 8,                                                \
                  &sV[BUF][w * 1024 + i * 512]);                               \
    }                                                                          \
  }

  STAGE(lo_c, 0);
  STAGE(lo_c + 32, 1);

  const int vbase_off = ln * 32 + ((g ^ ((ln >> 1) & 3)) << 3);

  int cb = 0;
  for (int it = 0; it < nt; ++it) {
    const int kb = lo_c + it * 32;
    // counted-vmcnt leading barrier: own tile-it loads complete, then block-wide
    if (it + 2 < nt) {
      int b2 = cb + 2;
      if (b2 >= 3) b2 -= 3;
      STAGE(kb + 64, b2);
      asm volatile("s_waitcnt vmcnt(8)" ::: "memory");
    } else if (it + 1 < nt) {
      asm volatile("s_waitcnt vmcnt(4)" ::: "memory");
    } else {
      asm volatile("s_waitcnt vmcnt(0)" ::: "memory");
    }
    __builtin_amdgcn_s_barrier();

    if (!(kb > qr0 + 31 || kb + 31 < qr0 - (WIN - 1))) {
      const u16* sk = sK[cb];
      const u16* sv = sV[cb];

      // S = K Q^T (swapped): sc[qf][kt], lane: q=qr0+qf*16+ln, k=kb+kt*16+g*4+j
      f32x4 sc[2][2] = {};
      __builtin_amdgcn_s_setprio(1);
#pragma unroll
      for (int c = 0; c < 4; ++c) {
        const int slot = (((c * 4 + g) ^ (ln & 7)) << 3);
        i32x4 k0 = *(const i32x4*)&sk[ln * 128 + slot];
        i32x4 k1 = *(const i32x4*)&sk[(16 + ln) * 128 + slot];
        mfma16(sc[0][0], k0, aq[0][c]);
        mfma16(sc[0][1], k1, aq[0][c]);
        mfma16(sc[1][0], k0, aq[1][c]);
        mfma16(sc[1][1], k1, aq[1][c]);
      }
      __builtin_amdgcn_s_setprio(0);

      // mask + scale
      float p[2][8];
      float mx[2];
      const bool interior = (kb + 31 <= qr0) && (qr0 + 31 - kb < WIN);
#pragma unroll
      for (int qf = 0; qf < 2; ++qf) {
        if (interior) {
#pragma unroll
          for (int j = 0; j < 4; ++j) {
            p[qf][j] = sc[qf][0][j] * scale;
            p[qf][4 + j] = sc[qf][1][j] * scale;
          }
        } else {
          const float NEG = -__builtin_inff();
          const int q = qr0 + qf * 16 + ln;
#pragma unroll
          for (int t = 0; t < 2; ++t)
#pragma unroll
            for (int j = 0; j < 4; ++j) {
              int k = kb + t * 16 + g * 4 + j;
              float s = sc[qf][t][j] * scale;
              p[qf][t * 4 + j] = (k <= q && q - k < WIN) ? s : NEG;
            }
        }
        float m = fmaxf(fmaxf(fmaxf(p[qf][0], p[qf][1]), fmaxf(p[qf][2], p[qf][3])),
                        fmaxf(fmaxf(p[qf][4], p[qf][5]), fmaxf(p[qf][6], p[qf][7])));
        m = fmaxf(m, __shfl_xor(m, 16));
        m = fmaxf(m, __shfl_xor(m, 32));
        mx[qf] = m;
      }

      // defer-max (T13): skip O-rescale unless max grew past THR=8
      float corr[2] = {1.f, 1.f};
      const bool noskip =
          !__all((mx[0] - mrun[0] <= 8.f) && (mx[1] - mrun[1] <= 8.f));
      if (noskip) {
#pragma unroll
        for (int qf = 0; qf < 2; ++qf) {
          float mnew = fmaxf(mrun[qf], mx[qf]);
          corr[qf] = __expf(mrun[qf] - mnew);
          mrun[qf] = mnew;
          f32x4 cv;
#pragma unroll
          for (int j = 0; j < 4; ++j) cv[j] = __shfl(corr[qf], g * 4 + j);
#pragma unroll
          for (int nf = 0; nf < 8; ++nf)
#pragma unroll
            for (int j = 0; j < 4; ++j) oacc[qf][nf][j] *= cv[j];
        }
      }

      i32x4 pa[2];
#pragma unroll
      for (int qf = 0; qf < 2; ++qf) {
#pragma unroll
        for (int e = 0; e < 8; ++e) p[qf][e] = __expf(p[qf][e] - mrun[qf]);
        float rs = ((p[qf][0] + p[qf][1]) + (p[qf][2] + p[qf][3])) +
                   ((p[qf][4] + p[qf][5]) + (p[qf][6] + p[qf][7]));
        rs += __shfl_xor(rs, 16);
        rs += __shfl_xor(rs, 32);
        lrun[qf] = lrun[qf] * corr[qf] + rs;
        pa[qf].x = (int)(f2bf_u(p[qf][0]) | (f2bf_u(p[qf][1]) << 16));
        pa[qf].y = (int)(f2bf_u(p[qf][2]) | (f2bf_u(p[qf][3]) << 16));
        pa[qf].z = (int)(f2bf_u(p[qf][4]) | (f2bf_u(p[qf][5]) << 16));
        pa[qf].w = (int)(f2bf_u(p[qf][6]) | (f2bf_u(p[qf][7]) << 16));
      }

      __builtin_amdgcn_s_setprio(1);
#pragma unroll
      for (int nf = 0; nf < 8; ++nf) {
        i32x4 vb = *(const i32x4*)&sv[vbase_off + nf * 512];
        mfma16(oacc[0][nf], pa[0], vb);
        mfma16(oacc[1][nf], pa[1], vb);
      }
      __builtin_amdgcn_s_setprio(0);
    }
    // trailing barrier: protects buf overwritten by next iteration's STAGE
    __builtin_amdgcn_s_barrier();
    cb = (cb == 2) ? 0 : cb + 1;
  }
#undef STAGE

  // write unnormalized partials
  const size_t pb = ((size_t)chunk * 16 + h) * S_LEN;
#pragma unroll
  for (int qf = 0; qf < 2; ++qf) {
    if (g == 0) {
      mpart[pb + qr0 + qf * 16 + ln] = mrun[qf];
      lpart[pb + qr0 + qf * 16 + ln] = lrun[qf];
    }
    u16* aop = opart + (pb + qr0 + qf * 16 + g * 4) * 128 + ln;
#pragma unroll
    for (int j = 0; j < 4; ++j)
#pragma unroll
      for (int nf = 0; nf < 8; ++nf)
        aop[(size_t)j * 128 + nf * 16] = (u16)f2bf_u(oacc[qf][nf][j]);
  }
}

// ---------------- combine the 2 KV-split partials -> AO bf16 ----------------
__global__ __launch_bounds__(256) void attn_combine_kernel(
    const u16* __restrict__ opart, const float* __restrict__ mpart,
    const float* __restrict__ lpart, u16* __restrict__ AO) {
  int t = blockIdx.x * 256 + threadIdx.x;  // 16*4096*16 threads
  int d0 = (t & 15) * 8;
  int rh = t >> 4;
  int row = rh & (S_LEN - 1);
  int h = rh >> 12;
  size_t i0 = (size_t)h * S_LEN + row;
  size_t i1 = i0 + (size_t)16 * S_LEN;
  float m0 = mpart[i0], m1 = mpart[i1];
  float l0 = lpart[i0], l1 = lpart[i1];
  float m = fmaxf(m0, m1);
  float w0 = __expf(m0 - m), w1 = __expf(m1 - m);
  float inv = 1.f / (l0 * w0 + l1 * w1);
  w0 *= inv;
  w1 *= inv;
  i32x4 v0 = *(const i32x4*)(opart + i0 * 128 + d0);
  i32x4 v1 = *(const i32x4*)(opart + i1 * 128 + d0);
  i32x4 ov;
#pragma unroll
  for (int j = 0; j < 4; ++j) {
    u32 a = ((u32)v0[j]), b = ((u32)v1[j]);
    float x = bf2f((u16)a) * w0 + bf2f((u16)b) * w1;
    float y = bf2f((u16)(a >> 16)) * w0 + bf2f((u16)(b >> 16)) * w1;
    ov[j] = (int)(f2bf_u(x) | (f2bf_u(y) << 16));
  }
  *(i32x4*)(AO + (size_t)row * HID + h * 128 + d0) = ov;
}

// ---------------- orchestration ----------------
extern "C" void kernel_launch(void* const* d_in, const int* in_sizes, int n_in,
                              void* d_out, int out_size, void* d_ws, size_t ws_size,
                              hipStream_t stream) {
  const float* hx = (const float*)d_in[0];
  const float* qw = (const float*)d_in[1];
  const float* kw = (const float*)d_in[2];
  const float* vw = (const float*)d_in[3];
  const float* ow = (const float*)d_in[4];

  char* p = (char*)d_ws;
  u16* Xb = (u16*)p; p += (size_t)S_LEN * HID * 2;
  u16* Wq = (u16*)p; p += (size_t)HID * HID * 2;
  u16* Wk = (u16*)p; p += (size_t)512 * HID * 2;
  u16* Wv = (u16*)p; p += (size_t)512 * HID * 2;
  u16* Wo = (u16*)p; p += (size_t)HID * HID * 2;
  u16* Qb = (u16*)p; p += (size_t)S_LEN * HID * 2;
  u16* Kb = (u16*)p; p += (size_t)S_LEN * 512 * 2;
  u16* Vt = (u16*)p; p += (size_t)S_LEN * 512 * 2;
  u16* AO = (u16*)p; p += (size_t)S_LEN * HID * 2;
  float* cs = (float*)p; p += (size_t)S_LEN * 64 * 4;
  float* sn = (float*)p; p += (size_t)S_LEN * 64 * 4;
  u16* Opart = (u16*)p; p += (size_t)2 * 16 * S_LEN * 128 * 2;  // 32 MB
  float* Mpart = (float*)p; p += (size_t)2 * 16 * S_LEN * 4;
  float* Lpart = (float*)p; p += (size_t)2 * 16 * S_LEN * 4;

  cvt_bf16_kernel<<<4096, 256, 0, stream>>>(hx, Xb, S_LEN * HID / 8);
  cvt_bf16_kernel<<<2048, 256, 0, stream>>>(qw, Wq, HID * HID / 8);
  cvt_bf16_kernel<<<512, 256, 0, stream>>>(kw, Wk, 512 * HID / 8);
  cvt_bf16_kernel<<<512, 256, 0, stream>>>(vw, Wv, 512 * HID / 8);
  cvt_bf16_kernel<<<2048, 256, 0, stream>>>(ow, Wo, HID * HID / 8);
  rope_table_kernel<<<S_LEN * 64 / 256, 256, 0, stream>>>(cs, sn);

  gemm_bt_kernel<0><<<dim3(16, 32), 256, 0, stream>>>(Xb, Wq, Qb, HID, HID);
  gemm_bt_kernel<0><<<dim3(4, 32), 256, 0, stream>>>(Xb, Wk, Kb, HID, 512);
  gemm_bt_kernel<1><<<dim3(4, 32), 256, 0, stream>>>(Xb, Wv, Vt, HID, 512);

  rope_apply_kernel<16><<<S_LEN * 16 * 16 / 256, 256, 0, stream>>>(Qb, cs, sn);
  rope_apply_kernel<4><<<S_LEN * 4 * 16 / 256, 256, 0, stream>>>(Kb, cs, sn);

  attn_kernel<<<1024, 256, 0, stream>>>(Qb, Kb, Vt, Opart, Mpart, Lpart);
  attn_combine_kernel<<<S_LEN * 16 * 16 / 256, 256, 0, stream>>>(Opart, Mpart,
                                                                 Lpart, AO);

  gemm_bt_kernel<2><<<dim3(16, 32), 256, 0, stream>>>(AO, Wo, d_out, HID, HID);
}

// Round 7
// 354.648 us; speedup vs baseline: 1.1345x; 1.1345x over previous
//
#include <hip/hip_runtime.h>
#include <stdint.h>

typedef unsigned short u16;
typedef unsigned int u32;
typedef float f32x4 __attribute__((ext_vector_type(4)));
typedef int   i32x4 __attribute__((ext_vector_type(4)));
typedef __bf16 bf16x8 __attribute__((ext_vector_type(8)));
typedef u16 u16x4 __attribute__((ext_vector_type(4)));

constexpr int S_LEN = 4096;
constexpr int HID   = 2048;
constexpr int WIN   = 2048;

__device__ __forceinline__ u32 f2bf_u(float f) {
  u32 u = __builtin_bit_cast(u32, f);
  return (u + 0x7fffu + ((u >> 16) & 1u)) >> 16;
}
__device__ __forceinline__ float bf2f(u16 u) {
  return __builtin_bit_cast(float, ((u32)u) << 16);
}
__device__ __forceinline__ void mfma16(f32x4& acc, i32x4 a, i32x4 b) {
  acc = __builtin_amdgcn_mfma_f32_16x16x32_bf16(
      __builtin_bit_cast(bf16x8, a), __builtin_bit_cast(bf16x8, b), acc, 0, 0, 0);
}
__device__ __forceinline__ void gload_lds16(const u16* g, u16* l) {
  __builtin_amdgcn_global_load_lds((const __attribute__((address_space(1))) u32*)g,
                                   (__attribute__((address_space(3))) u32*)l, 16, 0, 0);
}

// ---------------- fp32 -> bf16 convert (8 elems/thread) ----------------
__global__ __launch_bounds__(256) void cvt_bf16_kernel(const float* __restrict__ src,
                                                       u16* __restrict__ dst, int n8) {
  int t = blockIdx.x * 256 + threadIdx.x;
  if (t >= n8) return;
  const f32x4* s = (const f32x4*)src + (size_t)t * 2;
  f32x4 a = s[0], b = s[1];
  i32x4 o;
  o.x = (int)(f2bf_u(a.x) | (f2bf_u(a.y) << 16));
  o.y = (int)(f2bf_u(a.z) | (f2bf_u(a.w) << 16));
  o.z = (int)(f2bf_u(b.x) | (f2bf_u(b.y) << 16));
  o.w = (int)(f2bf_u(b.z) | (f2bf_u(b.w) << 16));
  *((i32x4*)dst + t) = o;
}

// ---------------- RoPE cos/sin table: [S][64] each ----------------
__global__ __launch_bounds__(256) void rope_table_kernel(float* __restrict__ cs,
                                                         float* __restrict__ sn) {
  int t = blockIdx.x * 256 + threadIdx.x;  // S*64 threads
  int d = t & 63, s = t >> 6;
  float inv = exp2f(-(float)d * 0.20762050593046014f);  // log2(10000)/64
  float f = (float)s * inv;
  cs[t] = cosf(f);
  sn[t] = sinf(f);
}

// ---------------- in-place RoPE on [S][NH*128] bf16, 4 d per thread -------
template <int NH>
__global__ __launch_bounds__(256) void rope_apply_kernel(u16* __restrict__ X,
                                                         const float* __restrict__ cs,
                                                         const float* __restrict__ sn) {
  int t = blockIdx.x * 256 + threadIdx.x;  // S*NH*16 threads
  int d0 = (t & 15) * 4;
  int r = t >> 4;
  int h = r % NH;
  int s = r / NH;
  f32x4 c = *(const f32x4*)&cs[(s << 6) | d0];
  f32x4 si = *(const f32x4*)&sn[(s << 6) | d0];
  u16* p = X + (size_t)s * (NH * 128) + h * 128 + d0;
  u16x4 a = *(u16x4*)p, b = *(u16x4*)(p + 64);
  u16x4 oa, ob;
#pragma unroll
  for (int j = 0; j < 4; ++j) {
    float x1 = bf2f(a[j]), x2 = bf2f(b[j]);
    oa[j] = (u16)f2bf_u(x1 * c[j] - x2 * si[j]);
    ob[j] = (u16)f2bf_u(x2 * c[j] + x1 * si[j]);
  }
  *(u16x4*)p = oa;
  *(u16x4*)(p + 64) = ob;
}

// ---------------- GEMM: C[M][N] = A[M][K] * B[N][K]^T, bf16 in, fp32 acc ----
// OUT_MODE 0: bf16 C[row*N+col]
// OUT_MODE 1: V tiled layout for attention (see attn_kernel PV fragment)
// OUT_MODE 2: fp32 C[row*N+col]
template <int OUT_MODE>
__global__ __launch_bounds__(256) void gemm_bt_kernel(const u16* __restrict__ A,
                                                      const u16* __restrict__ B,
                                                      void* __restrict__ Cv,
                                                      int K, int N) {
  __shared__ __attribute__((aligned(16))) u16 sA[128 * 64];
  __shared__ __attribute__((aligned(16))) u16 sB[128 * 64];
  const int lane = threadIdx.x & 63;
  const int w = threadIdx.x >> 6;
  const int g = lane >> 4, ln = lane & 15;

  // bijective XCD swizzle (nwg % 8 == 0 for all our grids)
  int wgid = blockIdx.y * gridDim.x + blockIdx.x;
  const int nwg = gridDim.x * gridDim.y;
  wgid = (wgid & 7) * (nwg >> 3) + (wgid >> 3);
  const int brow = (wgid / gridDim.x) * 128;
  const int bcol = (wgid % gridDim.x) * 128;
  const int wr = (w >> 1) * 64, wc = (w & 1) * 64;

  f32x4 acc[4][4] = {};

  const int sr = w * 32 + (lane >> 3);
  const int scol = (lane & 7) * 8;
  const u16* Abase = A + (size_t)(brow + sr) * K + scol;
  const u16* Bbase = B + (size_t)(bcol + sr) * K + scol;
  u16* sAdst = &sA[w * 2048];
  u16* sBdst = &sB[w * 2048];

  for (int k0 = 0; k0 < K; k0 += 64) {
    __syncthreads();
#pragma unroll
    for (int i = 0; i < 4; ++i) {
      gload_lds16(Abase + (size_t)i * 8 * K + k0, sAdst + i * 512);
      gload_lds16(Bbase + (size_t)i * 8 * K + k0, sBdst + i * 512);
    }
    __syncthreads();
#pragma unroll
    for (int kk = 0; kk < 2; ++kk) {
      i32x4 af[4], bfr[4];
#pragma unroll
      for (int m = 0; m < 4; ++m)
        af[m] = *(const i32x4*)&sA[(wr + m * 16 + ln) * 64 + kk * 32 + g * 8];
#pragma unroll
      for (int n = 0; n < 4; ++n)
        bfr[n] = *(const i32x4*)&sB[(wc + n * 16 + ln) * 64 + kk * 32 + g * 8];
#pragma unroll
      for (int m = 0; m < 4; ++m)
#pragma unroll
        for (int n = 0; n < 4; ++n) mfma16(acc[m][n], af[m], bfr[n]);
    }
  }

  const int orow0 = brow + wr + g * 4;
  const int ocol0 = bcol + wc + ln;
#pragma unroll
  for (int m = 0; m < 4; ++m)
#pragma unroll
    for (int n = 0; n < 4; ++n)
#pragma unroll
      for (int j = 0; j < 4; ++j) {
        int row = orow0 + m * 16 + j;
        int col = ocol0 + n * 16;
        float v = acc[m][n][j];
        if constexpr (OUT_MODE == 0) {
          ((u16*)Cv)[(size_t)row * N + col] = (u16)f2bf_u(v);
        } else if constexpr (OUT_MODE == 1) {
          // V tiled: row = s, col = kvh*128 + d
          int d = col & 127, kvh = col >> 7;
          int T = row >> 5, ks = row & 31;
          int t = ks >> 4, gg = (ks >> 2) & 3, e = (t << 2) | (ks & 3);
          size_t idx = (size_t)kvh * S_LEN * 128 + (size_t)T * 4096 +
                       (size_t)d * 32 + ((size_t)(gg ^ ((d >> 1) & 3)) << 3) + e;
          ((u16*)Cv)[idx] = (u16)f2bf_u(v);
        } else {
          ((float*)Cv)[(size_t)row * N + col] = v;
        }
      }
}

// ---------------- flash attention: barrier-free wave-flash ----------------
// 1 wave (64 thr) per block; 32 q-rows; 2-way KV-split; K/V global->regs
// (L2-resident panels, XCD-pinned: each XCD serves 2 heads = 1 kvh panel).
// grid 4096 = 16 h x 2 chunk x 128 q-groups, heavy-first within XCD.
__global__ __launch_bounds__(64) void attn_kernel(const u16* __restrict__ Q,
                                                  const u16* __restrict__ Kb,
                                                  const u16* __restrict__ Vt,
                                                  u16* __restrict__ opart,
                                                  float* __restrict__ mpart,
                                                  float* __restrict__ lpart) {
  const int lane = threadIdx.x;
  const int g = lane >> 4, ln = lane & 15;

  const int o = blockIdx.x;                     // 4096
  const int wgid = ((o & 7) << 9) | (o >> 3);   // XCD-pin: wgid/512 = XCD
  const int h = wgid >> 8;                      // 2 heads per XCD
  const int idx = wgid & 255;
  const int chunk = idx & 1;
  const int gq = 127 - (idx >> 1);              // heavy q-groups first
  const int kvh = h >> 2;
  const int qr0 = gq * 32;

  // Q fragments (B-operand): qf in {0,1}: rows qr0+qf*16+ln, d = c*32+g*8
  i32x4 aq[2][4];
#pragma unroll
  for (int qf = 0; qf < 2; ++qf) {
    const u16* qp = Q + (size_t)(qr0 + qf * 16 + ln) * HID + h * 128 + g * 8;
#pragma unroll
    for (int c = 0; c < 4; ++c) aq[qf][c] = *(const i32x4*)(qp + c * 32);
  }

  f32x4 oacc[2][8] = {};
  float mrun[2] = {-1e30f, -1e30f};
  float lrun[2] = {0.f, 0.f};

  int lo = qr0 - (WIN - 1);
  if (lo < 0) lo = 0;
  lo &= ~31;
  const int nt_full = ((qr0 + 32) - lo) >> 5;
  const int nt0 = nt_full >> 1;
  const int lo_c = lo + (chunk ? nt0 * 32 : 0);
  const int nt = chunk ? nt_full - nt0 : nt0;   // may be 0 (gq=0, chunk=0)

  // per-lane K base: row lo_c+ln (+t*16), d-chunk c*32+g*8
  const u16* kptr = Kb + (size_t)(lo_c + ln) * 512 + kvh * 128 + g * 8;
  // per-lane V base (tiled layout, swizzle matches producer OUT_MODE 1)
  const int vswz = (g ^ ((ln >> 1) & 3)) << 3;
  const u16* vptr = Vt + (size_t)kvh * S_LEN * 128 +
                    (size_t)(lo_c >> 5) * 4096 + ln * 32 + vswz;

  const float scale = 0.088388347648318447f;  // 1/sqrt(128)

  i32x4 kf[2][4], vf[8];
  if (nt > 0) {
#pragma unroll
    for (int t = 0; t < 2; ++t)
#pragma unroll
      for (int c = 0; c < 4; ++c)
        kf[t][c] = *(const i32x4*)(kptr + t * 8192 + c * 32);
#pragma unroll
    for (int nf = 0; nf < 8; ++nf) vf[nf] = *(const i32x4*)(vptr + nf * 512);
  }

  for (int it = 0; it < nt; ++it) {
    const int kb = lo_c + it * 32;
    const bool more = (it + 1 < nt);

    // S = K Q^T (swapped): lane q=qr0+qf*16+ln, k=kb+t*16+g*4+j
    f32x4 sc[2][2] = {};
    __builtin_amdgcn_s_setprio(1);
#pragma unroll
    for (int c = 0; c < 4; ++c) {
      mfma16(sc[0][0], kf[0][c], aq[0][c]);
      mfma16(sc[0][1], kf[1][c], aq[0][c]);
      mfma16(sc[1][0], kf[0][c], aq[1][c]);
      mfma16(sc[1][1], kf[1][c], aq[1][c]);
    }
    __builtin_amdgcn_s_setprio(0);

    // prefetch next K into freed kf regs (WAR keeps order; ~350cy to next use)
    if (more) {
      kptr += 32 * 512;
#pragma unroll
      for (int t = 0; t < 2; ++t)
#pragma unroll
        for (int c = 0; c < 4; ++c)
          kf[t][c] = *(const i32x4*)(kptr + t * 8192 + c * 32);
    }

    // mask + scale
    float p[2][8];
    float mx[2];
    const bool interior = (kb + 31 <= qr0) && (qr0 + 31 - kb < WIN);
#pragma unroll
    for (int qf = 0; qf < 2; ++qf) {
      if (interior) {
#pragma unroll
        for (int j = 0; j < 4; ++j) {
          p[qf][j] = sc[qf][0][j] * scale;
          p[qf][4 + j] = sc[qf][1][j] * scale;
        }
      } else {
        const float NEG = -__builtin_inff();
        const int q = qr0 + qf * 16 + ln;
#pragma unroll
        for (int t = 0; t < 2; ++t)
#pragma unroll
          for (int j = 0; j < 4; ++j) {
            int k = kb + t * 16 + g * 4 + j;
            float s = sc[qf][t][j] * scale;
            p[qf][t * 4 + j] = (k <= q && q - k < WIN) ? s : NEG;
          }
      }
      float m = fmaxf(fmaxf(fmaxf(p[qf][0], p[qf][1]), fmaxf(p[qf][2], p[qf][3])),
                      fmaxf(fmaxf(p[qf][4], p[qf][5]), fmaxf(p[qf][6], p[qf][7])));
      m = fmaxf(m, __shfl_xor(m, 16));
      m = fmaxf(m, __shfl_xor(m, 32));
      mx[qf] = m;
    }

    // defer-max (T13): skip O-rescale unless max grew past THR=8
    float corr[2] = {1.f, 1.f};
    const bool noskip =
        !__all((mx[0] - mrun[0] <= 8.f) && (mx[1] - mrun[1] <= 8.f));
    if (noskip) {
#pragma unroll
      for (int qf = 0; qf < 2; ++qf) {
        float mnew = fmaxf(mrun[qf], mx[qf]);
        corr[qf] = __expf(mrun[qf] - mnew);
        mrun[qf] = mnew;
        f32x4 cv;
#pragma unroll
        for (int j = 0; j < 4; ++j) cv[j] = __shfl(corr[qf], g * 4 + j);
#pragma unroll
        for (int nf = 0; nf < 8; ++nf)
#pragma unroll
          for (int j = 0; j < 4; ++j) oacc[qf][nf][j] *= cv[j];
      }
    }

    i32x4 pa[2];
#pragma unroll
    for (int qf = 0; qf < 2; ++qf) {
#pragma unroll
      for (int e = 0; e < 8; ++e) p[qf][e] = __expf(p[qf][e] - mrun[qf]);
      float rs = ((p[qf][0] + p[qf][1]) + (p[qf][2] + p[qf][3])) +
                 ((p[qf][4] + p[qf][5]) + (p[qf][6] + p[qf][7]));
      rs += __shfl_xor(rs, 16);
      rs += __shfl_xor(rs, 32);
      lrun[qf] = lrun[qf] * corr[qf] + rs;
      pa[qf].x = (int)(f2bf_u(p[qf][0]) | (f2bf_u(p[qf][1]) << 16));
      pa[qf].y = (int)(f2bf_u(p[qf][2]) | (f2bf_u(p[qf][3]) << 16));
      pa[qf].z = (int)(f2bf_u(p[qf][4]) | (f2bf_u(p[qf][5]) << 16));
      pa[qf].w = (int)(f2bf_u(p[qf][6]) | (f2bf_u(p[qf][7]) << 16));
    }

    __builtin_amdgcn_s_setprio(1);
#pragma unroll
    for (int nf = 0; nf < 8; ++nf) {
      mfma16(oacc[0][nf], pa[0], vf[nf]);
      mfma16(oacc[1][nf], pa[1], vf[nf]);
    }
    __builtin_amdgcn_s_setprio(0);

    // prefetch next V into freed vf regs (~350cy to next use)
    if (more) {
      vptr += 4096;
#pragma unroll
      for (int nf = 0; nf < 8; ++nf) vf[nf] = *(const i32x4*)(vptr + nf * 512);
    }
  }

  // write unnormalized partials
  const size_t pb = ((size_t)chunk * 16 + h) * S_LEN;
#pragma unroll
  for (int qf = 0; qf < 2; ++qf) {
    if (g == 0) {
      mpart[pb + qr0 + qf * 16 + ln] = mrun[qf];
      lpart[pb + qr0 + qf * 16 + ln] = lrun[qf];
    }
    u16* aop = opart + (pb + qr0 + qf * 16 + g * 4) * 128 + ln;
#pragma unroll
    for (int j = 0; j < 4; ++j)
#pragma unroll
      for (int nf = 0; nf < 8; ++nf)
        aop[(size_t)j * 128 + nf * 16] = (u16)f2bf_u(oacc[qf][nf][j]);
  }
}

// ---------------- combine the 2 KV-split partials -> AO bf16 ----------------
__global__ __launch_bounds__(256) void attn_combine_kernel(
    const u16* __restrict__ opart, const float* __restrict__ mpart,
    const float* __restrict__ lpart, u16* __restrict__ AO) {
  int t = blockIdx.x * 256 + threadIdx.x;  // 16*4096*16 threads
  int d0 = (t & 15) * 8;
  int rh = t >> 4;
  int row = rh & (S_LEN - 1);
  int h = rh >> 12;
  size_t i0 = (size_t)h * S_LEN + row;
  size_t i1 = i0 + (size_t)16 * S_LEN;
  float m0 = mpart[i0], m1 = mpart[i1];
  float l0 = lpart[i0], l1 = lpart[i1];
  float m = fmaxf(m0, m1);
  float w0 = __expf(m0 - m), w1 = __expf(m1 - m);
  float inv = 1.f / (l0 * w0 + l1 * w1);
  w0 *= inv;
  w1 *= inv;
  i32x4 v0 = *(const i32x4*)(opart + i0 * 128 + d0);
  i32x4 v1 = *(const i32x4*)(opart + i1 * 128 + d0);
  i32x4 ov;
#pragma unroll
  for (int j = 0; j < 4; ++j) {
    u32 a = ((u32)v0[j]), b = ((u32)v1[j]);
    float x = bf2f((u16)a) * w0 + bf2f((u16)b) * w1;
    float y = bf2f((u16)(a >> 16)) * w0 + bf2f((u16)(b >> 16)) * w1;
    ov[j] = (int)(f2bf_u(x) | (f2bf_u(y) << 16));
  }
  *(i32x4*)(AO + (size_t)row * HID + h * 128 + d0) = ov;
}

// ---------------- orchestration ----------------
extern "C" void kernel_launch(void* const* d_in, const int* in_sizes, int n_in,
                              void* d_out, int out_size, void* d_ws, size_t ws_size,
                              hipStream_t stream) {
  const float* hx = (const float*)d_in[0];
  const float* qw = (const float*)d_in[1];
  const float* kw = (const float*)d_in[2];
  const float* vw = (const float*)d_in[3];
  const float* ow = (const float*)d_in[4];

  char* p = (char*)d_ws;
  u16* Xb = (u16*)p; p += (size_t)S_LEN * HID * 2;
  u16* Wq = (u16*)p; p += (size_t)HID * HID * 2;
  u16* Wk = (u16*)p; p += (size_t)512 * HID * 2;
  u16* Wv = (u16*)p; p += (size_t)512 * HID * 2;
  u16* Wo = (u16*)p; p += (size_t)HID * HID * 2;
  u16* Qb = (u16*)p; p += (size_t)S_LEN * HID * 2;
  u16* Kb = (u16*)p; p += (size_t)S_LEN * 512 * 2;
  u16* Vt = (u16*)p; p += (size_t)S_LEN * 512 * 2;
  u16* AO = (u16*)p; p += (size_t)S_LEN * HID * 2;
  float* cs = (float*)p; p += (size_t)S_LEN * 64 * 4;
  float* sn = (float*)p; p += (size_t)S_LEN * 64 * 4;
  u16* Opart = (u16*)p; p += (size_t)2 * 16 * S_LEN * 128 * 2;  // 32 MB
  float* Mpart = (float*)p; p += (size_t)2 * 16 * S_LEN * 4;
  float* Lpart = (float*)p; p += (size_t)2 * 16 * S_LEN * 4;

  cvt_bf16_kernel<<<4096, 256, 0, stream>>>(hx, Xb, S_LEN * HID / 8);
  cvt_bf16_kernel<<<2048, 256, 0, stream>>>(qw, Wq, HID * HID / 8);
  cvt_bf16_kernel<<<512, 256, 0, stream>>>(kw, Wk, 512 * HID / 8);
  cvt_bf16_kernel<<<512, 256, 0, stream>>>(vw, Wv, 512 * HID / 8);
  cvt_bf16_kernel<<<2048, 256, 0, stream>>>(ow, Wo, HID * HID / 8);
  rope_table_kernel<<<S_LEN * 64 / 256, 256, 0, stream>>>(cs, sn);

  gemm_bt_kernel<0><<<dim3(16, 32), 256, 0, stream>>>(Xb, Wq, Qb, HID, HID);
  gemm_bt_kernel<0><<<dim3(4, 32), 256, 0, stream>>>(Xb, Wk, Kb, HID, 512);
  gemm_bt_kernel<1><<<dim3(4, 32), 256, 0, stream>>>(Xb, Wv, Vt, HID, 512);

  rope_apply_kernel<16><<<S_LEN * 16 * 16 / 256, 256, 0, stream>>>(Qb, cs, sn);
  rope_apply_kernel<4><<<S_LEN * 4 * 16 / 256, 256, 0, stream>>>(Kb, cs, sn);

  attn_kernel<<<4096, 64, 0, stream>>>(Qb, Kb, Vt, Opart, Mpart, Lpart);
  attn_combine_kernel<<<S_LEN * 16 * 16 / 256, 256, 0, stream>>>(Opart, Mpart,
                                                                 Lpart, AO);

  gemm_bt_kernel<2><<<dim3(16, 32), 256, 0, stream>>>(AO, Wo, d_out, HID, HID);
}

// Round 8
// 315.611 us; speedup vs baseline: 1.2749x; 1.1237x over previous
//
#include <hip/hip_runtime.h>
#include <stdint.h>

typedef unsigned short u16;
typedef unsigned int u32;
typedef float f32x4 __attribute__((ext_vector_type(4)));
typedef float f32x8 __attribute__((ext_vector_type(8)));
typedef int   i32x4 __attribute__((ext_vector_type(4)));
typedef __bf16 bf16x8 __attribute__((ext_vector_type(8)));
typedef u16 u16x4 __attribute__((ext_vector_type(4)));

constexpr int S_LEN = 4096;
constexpr int HID   = 2048;
constexpr int WIN   = 2048;

__device__ __forceinline__ u32 f2bf_u(float f) {
  u32 u = __builtin_bit_cast(u32, f);
  return (u + 0x7fffu + ((u >> 16) & 1u)) >> 16;
}
__device__ __forceinline__ float bf2f(u16 u) {
  return __builtin_bit_cast(float, ((u32)u) << 16);
}
__device__ __forceinline__ float exp2x(float x) {
#if __has_builtin(__builtin_amdgcn_exp2f)
  return __builtin_amdgcn_exp2f(x);
#else
  return exp2f(x);
#endif
}
__device__ __forceinline__ void mfma16(f32x4& acc, i32x4 a, i32x4 b) {
  acc = __builtin_amdgcn_mfma_f32_16x16x32_bf16(
      __builtin_bit_cast(bf16x8, a), __builtin_bit_cast(bf16x8, b), acc, 0, 0, 0);
}
__device__ __forceinline__ void gload_lds16(const u16* g, u16* l) {
  __builtin_amdgcn_global_load_lds((const __attribute__((address_space(1))) u32*)g,
                                   (__attribute__((address_space(3))) u32*)l, 16, 0, 0);
}

// ---------------- fused fp32 -> bf16 convert, all 5 tensors ----------------
constexpr int CVT_B0 = 1048576;            // X
constexpr int CVT_B1 = CVT_B0 + 524288;    // +Wq
constexpr int CVT_B2 = CVT_B1 + 131072;    // +Wk
constexpr int CVT_B3 = CVT_B2 + 131072;    // +Wv
constexpr int CVT_B4 = CVT_B3 + 524288;    // +Wo  (total threads, 8 elem each)

__global__ __launch_bounds__(256) void cvt_all_kernel(
    const float* __restrict__ s0, const float* __restrict__ s1,
    const float* __restrict__ s2, const float* __restrict__ s3,
    const float* __restrict__ s4, u16* __restrict__ d0, u16* __restrict__ d1,
    u16* __restrict__ d2, u16* __restrict__ d3, u16* __restrict__ d4) {
  int t = blockIdx.x * 256 + threadIdx.x;
  const float* s;
  u16* d;
  int off;
  if (t < CVT_B0) { s = s0; d = d0; off = t; }
  else if (t < CVT_B1) { s = s1; d = d1; off = t - CVT_B0; }
  else if (t < CVT_B2) { s = s2; d = d2; off = t - CVT_B1; }
  else if (t < CVT_B3) { s = s3; d = d3; off = t - CVT_B2; }
  else { s = s4; d = d4; off = t - CVT_B3; }
  const f32x4* sp = (const f32x4*)s + (size_t)off * 2;
  f32x4 a = sp[0], b = sp[1];
  i32x4 o;
  o.x = (int)(f2bf_u(a.x) | (f2bf_u(a.y) << 16));
  o.y = (int)(f2bf_u(a.z) | (f2bf_u(a.w) << 16));
  o.z = (int)(f2bf_u(b.x) | (f2bf_u(b.y) << 16));
  o.w = (int)(f2bf_u(b.z) | (f2bf_u(b.w) << 16));
  *((i32x4*)d + off) = o;
}

// ---------------- RoPE cos/sin table: [S][64] each ----------------
__global__ __launch_bounds__(256) void rope_table_kernel(float* __restrict__ cs,
                                                         float* __restrict__ sn) {
  int t = blockIdx.x * 256 + threadIdx.x;  // S*64 threads
  int d = t & 63, s = t >> 6;
  float inv = exp2f(-(float)d * 0.20762050593046014f);  // log2(10000)/64
  float f = (float)s * inv;
  cs[t] = cosf(f);
  sn[t] = sinf(f);
}

// ---------------- fused in-place RoPE on Q (scaled) and K ----------------
// Q additionally multiplied by 1/sqrt(128)*log2(e) (softmax runs in exp2 domain)
__global__ __launch_bounds__(256) void rope_qk_kernel(u16* __restrict__ Qb,
                                                      u16* __restrict__ Kb,
                                                      const float* __restrict__ cs,
                                                      const float* __restrict__ sn) {
  const float SC2 = 0.088388347648318447f * 1.4426950408889634f;
  int t = blockIdx.x * 256 + threadIdx.x;  // S*(16+4)*16 threads
  int d0 = (t & 15) * 4;
  int r = t >> 4;
  u16* p;
  int s;
  float qs;
  if (r < S_LEN * 16) {
    int h = r & 15; s = r >> 4;
    p = Qb + (size_t)s * HID + h * 128 + d0;
    qs = SC2;
  } else {
    int r2 = r - S_LEN * 16;
    int h = r2 & 3; s = r2 >> 2;
    p = Kb + (size_t)s * 512 + h * 128 + d0;
    qs = 1.f;
  }
  f32x4 c = *(const f32x4*)&cs[(s << 6) | d0];
  f32x4 si = *(const f32x4*)&sn[(s << 6) | d0];
  u16x4 a = *(u16x4*)p, b = *(u16x4*)(p + 64);
  u16x4 oa, ob;
#pragma unroll
  for (int j = 0; j < 4; ++j) {
    float x1 = bf2f(a[j]), x2 = bf2f(b[j]);
    oa[j] = (u16)f2bf_u((x1 * c[j] - x2 * si[j]) * qs);
    ob[j] = (u16)f2bf_u((x2 * c[j] + x1 * si[j]) * qs);
  }
  *(u16x4*)p = oa;
  *(u16x4*)(p + 64) = ob;
}

// ---------------- fused QKV GEMM: X[4096x2048] x {Wq,Wk,Wv}^T ----------------
// grid 768 blocks (24 col-tiles x 32 row-tiles), XCD-swizzled.
// cols 0-2047 -> Qb row-major; 2048-2559 -> Kb row-major; 2560-3071 -> Vt tiled.
__global__ __launch_bounds__(256) void qkv_gemm_kernel(
    const u16* __restrict__ A, const u16* __restrict__ Wq,
    const u16* __restrict__ Wk, const u16* __restrict__ Wv,
    u16* __restrict__ Qb, u16* __restrict__ Kb, u16* __restrict__ Vt) {
  __shared__ __attribute__((aligned(16))) u16 sA[128 * 64];
  __shared__ __attribute__((aligned(16))) u16 sB[128 * 64];
  const int lane = threadIdx.x & 63;
  const int w = threadIdx.x >> 6;
  const int g = lane >> 4, ln = lane & 15;
  const int K = HID;

  int wgid = blockIdx.x;                 // 768
  wgid = (wgid & 7) * 96 + (wgid >> 3);  // bijective XCD swizzle
  const int brow = (wgid / 24) * 128;
  const int bcol = (wgid % 24) * 128;

  const u16* B;
  u16* out;
  int bc, mode, N;
  if (bcol < 2048)      { B = Wq; out = Qb; bc = bcol;        N = 2048; mode = 0; }
  else if (bcol < 2560) { B = Wk; out = Kb; bc = bcol - 2048; N = 512;  mode = 0; }
  else                  { B = Wv; out = Vt; bc = bcol - 2560; N = 512;  mode = 1; }

  const int wr = (w >> 1) * 64, wc = (w & 1) * 64;
  f32x4 acc[4][4] = {};

  const int sr = w * 32 + (lane >> 3);
  const int scol = (lane & 7) * 8;
  const u16* Abase = A + (size_t)(brow + sr) * K + scol;
  const u16* Bbase = B + (size_t)(bc + sr) * K + scol;
  u16* sAdst = &sA[w * 2048];
  u16* sBdst = &sB[w * 2048];

  for (int k0 = 0; k0 < K; k0 += 64) {
    __syncthreads();
#pragma unroll
    for (int i = 0; i < 4; ++i) {
      gload_lds16(Abase + (size_t)i * 8 * K + k0, sAdst + i * 512);
      gload_lds16(Bbase + (size_t)i * 8 * K + k0, sBdst + i * 512);
    }
    __syncthreads();
#pragma unroll
    for (int kk = 0; kk < 2; ++kk) {
      i32x4 af[4], bfr[4];
#pragma unroll
      for (int m = 0; m < 4; ++m)
        af[m] = *(const i32x4*)&sA[(wr + m * 16 + ln) * 64 + kk * 32 + g * 8];
#pragma unroll
      for (int n = 0; n < 4; ++n)
        bfr[n] = *(const i32x4*)&sB[(wc + n * 16 + ln) * 64 + kk * 32 + g * 8];
#pragma unroll
      for (int m = 0; m < 4; ++m)
#pragma unroll
        for (int n = 0; n < 4; ++n) mfma16(acc[m][n], af[m], bfr[n]);
    }
  }

  const int orow0 = brow + wr + g * 4;
  const int ocol0 = bc + wc + ln;
#pragma unroll
  for (int m = 0; m < 4; ++m)
#pragma unroll
    for (int n = 0; n < 4; ++n)
#pragma unroll
      for (int j = 0; j < 4; ++j) {
        int row = orow0 + m * 16 + j;
        int col = ocol0 + n * 16;
        float v = acc[m][n][j];
        if (mode == 0) {
          out[(size_t)row * N + col] = (u16)f2bf_u(v);
        } else {
          int d = col & 127, kvh = col >> 7;
          int T = row >> 5, ks = row & 31;
          int tt = ks >> 4, gg = (ks >> 2) & 3, e = (tt << 2) | (ks & 3);
          size_t idx = (size_t)kvh * S_LEN * 128 + (size_t)T * 4096 +
                       (size_t)d * 32 + ((size_t)(gg ^ ((d >> 1) & 3)) << 3) + e;
          out[idx] = (u16)f2bf_u(v);
        }
      }
}

// ---------------- O-projection GEMM: fp32 out ----------------
__global__ __launch_bounds__(256) void gemm_o_kernel(const u16* __restrict__ A,
                                                     const u16* __restrict__ B,
                                                     float* __restrict__ Cv,
                                                     int K, int N) {
  __shared__ __attribute__((aligned(16))) u16 sA[128 * 64];
  __shared__ __attribute__((aligned(16))) u16 sB[128 * 64];
  const int lane = threadIdx.x & 63;
  const int w = threadIdx.x >> 6;
  const int g = lane >> 4, ln = lane & 15;

  int wgid = blockIdx.y * gridDim.x + blockIdx.x;
  const int nwg = gridDim.x * gridDim.y;
  wgid = (wgid & 7) * (nwg >> 3) + (wgid >> 3);
  const int brow = (wgid / gridDim.x) * 128;
  const int bcol = (wgid % gridDim.x) * 128;
  const int wr = (w >> 1) * 64, wc = (w & 1) * 64;

  f32x4 acc[4][4] = {};

  const int sr = w * 32 + (lane >> 3);
  const int scol = (lane & 7) * 8;
  const u16* Abase = A + (size_t)(brow + sr) * K + scol;
  const u16* Bbase = B + (size_t)(bcol + sr) * K + scol;
  u16* sAdst = &sA[w * 2048];
  u16* sBdst = &sB[w * 2048];

  for (int k0 = 0; k0 < K; k0 += 64) {
    __syncthreads();
#pragma unroll
    for (int i = 0; i < 4; ++i) {
      gload_lds16(Abase + (size_t)i * 8 * K + k0, sAdst + i * 512);
      gload_lds16(Bbase + (size_t)i * 8 * K + k0, sBdst + i * 512);
    }
    __syncthreads();
#pragma unroll
    for (int kk = 0; kk < 2; ++kk) {
      i32x4 af[4], bfr[4];
#pragma unroll
      for (int m = 0; m < 4; ++m)
        af[m] = *(const i32x4*)&sA[(wr + m * 16 + ln) * 64 + kk * 32 + g * 8];
#pragma unroll
      for (int n = 0; n < 4; ++n)
        bfr[n] = *(const i32x4*)&sB[(wc + n * 16 + ln) * 64 + kk * 32 + g * 8];
#pragma unroll
      for (int m = 0; m < 4; ++m)
#pragma unroll
        for (int n = 0; n < 4; ++n) mfma16(acc[m][n], af[m], bfr[n]);
    }
  }

  const int orow0 = brow + wr + g * 4;
  const int ocol0 = bcol + wc + ln;
#pragma unroll
  for (int m = 0; m < 4; ++m)
#pragma unroll
    for (int n = 0; n < 4; ++n)
#pragma unroll
      for (int j = 0; j < 4; ++j)
        Cv[(size_t)(orow0 + m * 16 + j) * N + ocol0 + n * 16] = acc[m][n][j];
}

// ---------------- flash attention: barrier-free wave-flash ----------------
// 1 wave per block; 32 q-rows; 2-way KV-split; K/V global->regs; exp2-domain
// softmax (Q pre-scaled by 1/sqrt(d)*log2e in rope_qk).
__global__ __launch_bounds__(64) void attn_kernel(const u16* __restrict__ Q,
                                                  const u16* __restrict__ Kb,
                                                  const u16* __restrict__ Vt,
                                                  u16* __restrict__ opart,
                                                  float* __restrict__ mpart,
                                                  float* __restrict__ lpart) {
  const int lane = threadIdx.x;
  const int g = lane >> 4, ln = lane & 15;

  const int o = blockIdx.x;                     // 4096
  const int wgid = ((o & 7) << 9) | (o >> 3);   // XCD-pin: 2 heads per XCD
  const int h = wgid >> 8;
  const int idx = wgid & 255;
  const int chunk = idx & 1;
  const int gq = 127 - (idx >> 1);              // heavy q-groups first
  const int kvh = h >> 2;
  const int qr0 = gq * 32;

  i32x4 aq[2][4];
#pragma unroll
  for (int qf = 0; qf < 2; ++qf) {
    const u16* qp = Q + (size_t)(qr0 + qf * 16 + ln) * HID + h * 128 + g * 8;
#pragma unroll
    for (int c = 0; c < 4; ++c) aq[qf][c] = *(const i32x4*)(qp + c * 32);
  }

  f32x4 oacc[2][8] = {};
  float mrun[2] = {-1e30f, -1e30f};
  float lrun[2] = {0.f, 0.f};  // per-lane partial; cross-lane reduce at end

  int lo = qr0 - (WIN - 1);
  if (lo < 0) lo = 0;
  lo &= ~31;
  const int nt_full = ((qr0 + 32) - lo) >> 5;
  const int nt0 = nt_full >> 1;
  const int lo_c = lo + (chunk ? nt0 * 32 : 0);
  const int nt = chunk ? nt_full - nt0 : nt0;

  const u16* kptr = Kb + (size_t)(lo_c + ln) * 512 + kvh * 128 + g * 8;
  const int vswz = (g ^ ((ln >> 1) & 3)) << 3;
  const u16* vptr = Vt + (size_t)kvh * S_LEN * 128 +
                    (size_t)(lo_c >> 5) * 4096 + ln * 32 + vswz;

  i32x4 kf[2][4], vf[8];
  if (nt > 0) {
#pragma unroll
    for (int t = 0; t < 2; ++t)
#pragma unroll
      for (int c = 0; c < 4; ++c)
        kf[t][c] = *(const i32x4*)(kptr + t * 8192 + c * 32);
#pragma unroll
    for (int nf = 0; nf < 8; ++nf) vf[nf] = *(const i32x4*)(vptr + nf * 512);
  }

  for (int it = 0; it < nt; ++it) {
    const int kb = lo_c + it * 32;
    const bool more = (it + 1 < nt);

    // S = K Q^T (swapped): lane q-col=qf*16+ln, k=kb+t*16+g*4+j; exp2 domain
    f32x4 sc[2][2] = {};
    __builtin_amdgcn_s_setprio(1);
#pragma unroll
    for (int c = 0; c < 4; ++c) {
      mfma16(sc[0][0], kf[0][c], aq[0][c]);
      mfma16(sc[0][1], kf[1][c], aq[0][c]);
      mfma16(sc[1][0], kf[0][c], aq[1][c]);
      mfma16(sc[1][1], kf[1][c], aq[1][c]);
    }
    __builtin_amdgcn_s_setprio(0);

    if (more) {
      kptr += 32 * 512;
#pragma unroll
      for (int t = 0; t < 2; ++t)
#pragma unroll
        for (int c = 0; c < 4; ++c)
          kf[t][c] = *(const i32x4*)(kptr + t * 8192 + c * 32);
    }

    float p[2][8];
    float mx[2];
    const bool interior = (kb + 31 <= qr0) && (qr0 + 31 - kb < WIN);
#pragma unroll
    for (int qf = 0; qf < 2; ++qf) {
      if (interior) {
#pragma unroll
        for (int j = 0; j < 4; ++j) {
          p[qf][j] = sc[qf][0][j];
          p[qf][4 + j] = sc[qf][1][j];
        }
      } else {
        const float NEG = -__builtin_inff();
        const int q = qr0 + qf * 16 + ln;
#pragma unroll
        for (int t = 0; t < 2; ++t)
#pragma unroll
          for (int j = 0; j < 4; ++j) {
            int k = kb + t * 16 + g * 4 + j;
            p[qf][t * 4 + j] = (k <= q && q - k < WIN) ? sc[qf][t][j] : NEG;
          }
      }
      // max3-friendly reduction tree
      float x0 = fmaxf(fmaxf(p[qf][0], p[qf][1]), p[qf][2]);
      float x1 = fmaxf(fmaxf(p[qf][3], p[qf][4]), p[qf][5]);
      float x2 = fmaxf(fmaxf(p[qf][6], p[qf][7]), x0);
      float m = fmaxf(x1, x2);
      m = fmaxf(m, __shfl_xor(m, 16));
      m = fmaxf(m, __shfl_xor(m, 32));
      mx[qf] = m;
    }

    // defer-max (T13): THR=11 in log2 domain ~ e^8-equivalent headroom
    float corr[2] = {1.f, 1.f};
    const bool noskip =
        !__all((mx[0] - mrun[0] <= 11.f) && (mx[1] - mrun[1] <= 11.f));
    if (noskip) {
#pragma unroll
      for (int qf = 0; qf < 2; ++qf) {
        float mnew = fmaxf(mrun[qf], mx[qf]);
        corr[qf] = exp2x(mrun[qf] - mnew);
        mrun[qf] = mnew;
        f32x4 cv;
#pragma unroll
        for (int j = 0; j < 4; ++j) cv[j] = __shfl(corr[qf], g * 4 + j);
#pragma unroll
        for (int nf = 0; nf < 8; ++nf)
#pragma unroll
          for (int j = 0; j < 4; ++j) oacc[qf][nf][j] *= cv[j];
      }
    }

    i32x4 pa[2];
#pragma unroll
    for (int qf = 0; qf < 2; ++qf) {
      f32x8 pv;
#pragma unroll
      for (int e = 0; e < 8; ++e) pv[e] = exp2x(p[qf][e] - mrun[qf]);
      float rs = ((pv[0] + pv[1]) + (pv[2] + pv[3])) +
                 ((pv[4] + pv[5]) + (pv[6] + pv[7]));
      lrun[qf] = lrun[qf] * corr[qf] + rs;  // per-lane partial
      bf16x8 pb = __builtin_convertvector(pv, bf16x8);
      pa[qf] = __builtin_bit_cast(i32x4, pb);
    }

    __builtin_amdgcn_s_setprio(1);
#pragma unroll
    for (int nf = 0; nf < 8; ++nf) {
      mfma16(oacc[0][nf], pa[0], vf[nf]);
      mfma16(oacc[1][nf], pa[1], vf[nf]);
    }
    __builtin_amdgcn_s_setprio(0);

    if (more) {
      vptr += 4096;
#pragma unroll
      for (int nf = 0; nf < 8; ++nf) vf[nf] = *(const i32x4*)(vptr + nf * 512);
    }
  }

  // finish deferred cross-lane l reduction
#pragma unroll
  for (int qf = 0; qf < 2; ++qf) {
    float l = lrun[qf];
    l += __shfl_xor(l, 16);
    l += __shfl_xor(l, 32);
    lrun[qf] = l;
  }

  const size_t pb = ((size_t)chunk * 16 + h) * S_LEN;
#pragma unroll
  for (int qf = 0; qf < 2; ++qf) {
    if (g == 0) {
      mpart[pb + qr0 + qf * 16 + ln] = mrun[qf];  // log2-domain
      lpart[pb + qr0 + qf * 16 + ln] = lrun[qf];
    }
    u16* aop = opart + (pb + qr0 + qf * 16 + g * 4) * 128 + ln;
#pragma unroll
    for (int j = 0; j < 4; ++j)
#pragma unroll
      for (int nf = 0; nf < 8; ++nf)
        aop[(size_t)j * 128 + nf * 16] = (u16)f2bf_u(oacc[qf][nf][j]);
  }
}

// ---------------- combine partials (log2-domain m) -> AO bf16 ----------------
__global__ __launch_bounds__(256) void attn_combine_kernel(
    const u16* __restrict__ opart, const float* __restrict__ mpart,
    const float* __restrict__ lpart, u16* __restrict__ AO) {
  int t = blockIdx.x * 256 + threadIdx.x;  // 16*4096*16 threads
  int d0 = (t & 15) * 8;
  int rh = t >> 4;
  int row = rh & (S_LEN - 1);
  int h = rh >> 12;
  size_t i0 = (size_t)h * S_LEN + row;
  size_t i1 = i0 + (size_t)16 * S_LEN;
  float m0 = mpart[i0], m1 = mpart[i1];
  float l0 = lpart[i0], l1 = lpart[i1];
  float m = fmaxf(m0, m1);
  float w0 = exp2x(m0 - m), w1 = exp2x(m1 - m);
  float inv = 1.f / (l0 * w0 + l1 * w1);
  w0 *= inv;
  w1 *= inv;
  i32x4 v0 = *(const i32x4*)(opart + i0 * 128 + d0);
  i32x4 v1 = *(const i32x4*)(opart + i1 * 128 + d0);
  i32x4 ov;
#pragma unroll
  for (int j = 0; j < 4; ++j) {
    u32 a = ((u32)v0[j]), b = ((u32)v1[j]);
    float x = bf2f((u16)a) * w0 + bf2f((u16)b) * w1;
    float y = bf2f((u16)(a >> 16)) * w0 + bf2f((u16)(b >> 16)) * w1;
    ov[j] = (int)(f2bf_u(x) | (f2bf_u(y) << 16));
  }
  *(i32x4*)(AO + (size_t)row * HID + h * 128 + d0) = ov;
}

// ---------------- orchestration ----------------
extern "C" void kernel_launch(void* const* d_in, const int* in_sizes, int n_in,
                              void* d_out, int out_size, void* d_ws, size_t ws_size,
                              hipStream_t stream) {
  const float* hx = (const float*)d_in[0];
  const float* qw = (const float*)d_in[1];
  const float* kw = (const float*)d_in[2];
  const float* vw = (const float*)d_in[3];
  const float* ow = (const float*)d_in[4];

  char* p = (char*)d_ws;
  u16* Xb = (u16*)p; p += (size_t)S_LEN * HID * 2;
  u16* Wq = (u16*)p; p += (size_t)HID * HID * 2;
  u16* Wk = (u16*)p; p += (size_t)512 * HID * 2;
  u16* Wv = (u16*)p; p += (size_t)512 * HID * 2;
  u16* Wo = (u16*)p; p += (size_t)HID * HID * 2;
  u16* Qb = (u16*)p; p += (size_t)S_LEN * HID * 2;
  u16* Kb = (u16*)p; p += (size_t)S_LEN * 512 * 2;
  u16* Vt = (u16*)p; p += (size_t)S_LEN * 512 * 2;
  u16* AO = (u16*)p; p += (size_t)S_LEN * HID * 2;
  float* cs = (float*)p; p += (size_t)S_LEN * 64 * 4;
  float* sn = (float*)p; p += (size_t)S_LEN * 64 * 4;
  u16* Opart = (u16*)p; p += (size_t)2 * 16 * S_LEN * 128 * 2;  // 32 MB
  float* Mpart = (float*)p; p += (size_t)2 * 16 * S_LEN * 4;
  float* Lpart = (float*)p; p += (size_t)2 * 16 * S_LEN * 4;

  cvt_all_kernel<<<CVT_B4 / 256, 256, 0, stream>>>(hx, qw, kw, vw, ow, Xb, Wq,
                                                   Wk, Wv, Wo);
  rope_table_kernel<<<S_LEN * 64 / 256, 256, 0, stream>>>(cs, sn);

  qkv_gemm_kernel<<<768, 256, 0, stream>>>(Xb, Wq, Wk, Wv, Qb, Kb, Vt);

  rope_qk_kernel<<<S_LEN * 20 * 16 / 256, 256, 0, stream>>>(Qb, Kb, cs, sn);

  attn_kernel<<<4096, 64, 0, stream>>>(Qb, Kb, Vt, Opart, Mpart, Lpart);
  attn_combine_kernel<<<S_LEN * 16 * 16 / 256, 256, 0, stream>>>(Opart, Mpart,
                                                                 Lpart, AO);

  gemm_o_kernel<<<dim3(16, 32), 256, 0, stream>>>(AO, Wo, (float*)d_out, HID,
                                                  HID);
}